// Round 1
// baseline (837.577 us; speedup 1.0000x reference)
//
#include <hip/hip_runtime.h>
#include <hip/hip_bf16.h>

// ---- problem dims (fixed) ----
#define Bdim 4
#define Ldim 512
#define Ddim 768
#define Kspan 96
#define Hdim 3072
#define Pdim 9120      // Kspan*(Kspan-1)
#define MROWS 384      // Bdim*Kspan

typedef __bf16 bf16x8 __attribute__((ext_vector_type(8)));
typedef float f32x4 __attribute__((ext_vector_type(4)));
typedef unsigned short ushort8v __attribute__((ext_vector_type(8)));

static __device__ __forceinline__ unsigned short f2bf(float x){
  return __builtin_bit_cast(unsigned short, (__bf16)x);
}
static __device__ __forceinline__ float bf2f(unsigned short u){
  return (float)__builtin_bit_cast(__bf16, u);
}

// ---------------- transpose + convert: W[K][N] fp32 -> WT[N][K] bf16 hi(+lo) ----------------
__global__ __launch_bounds__(256) void transpose_split(
    const float* __restrict__ W, unsigned short* __restrict__ WTh,
    unsigned short* __restrict__ WTl, int K, int N)
{
  __shared__ float tile[64][65];
  int k0 = blockIdx.y * 64, n0 = blockIdx.x * 64;
  int c = threadIdx.x & 63, r0 = threadIdx.x >> 6;
  for (int p = 0; p < 16; p++){
    int r = r0 + p * 4;
    tile[c][r] = W[(size_t)(k0 + r) * N + n0 + c];
  }
  __syncthreads();
  for (int p = 0; p < 16; p++){
    int n = r0 + p * 4;
    float x = tile[n][c];
    unsigned short h = f2bf(x);
    size_t o = (size_t)(n0 + n) * K + k0 + c;
    WTh[o] = h;
    WTl[o] = f2bf(x - bf2f(h));
  }
}

__global__ __launch_bounds__(256) void transpose_cvt1(
    const float* __restrict__ W, unsigned short* __restrict__ WT, int K, int N)
{
  __shared__ float tile[64][65];
  int k0 = blockIdx.y * 64, n0 = blockIdx.x * 64;
  int c = threadIdx.x & 63, r0 = threadIdx.x >> 6;
  for (int p = 0; p < 16; p++){
    int r = r0 + p * 4;
    tile[c][r] = W[(size_t)(k0 + r) * N + n0 + c];
  }
  __syncthreads();
  for (int p = 0; p < 16; p++){
    int n = r0 + p * 4;
    WT[(size_t)(n0 + n) * K + k0 + c] = f2bf(tile[n][c]);
  }
}

// ---------------- gather h rows at span indices (fp32 copy) ----------------
// hg: [2][MROWS][Ddim]; first 384 rows = start-gather, next 384 = end-gather
__global__ __launch_bounds__(256) void gather_rows(
    const float* __restrict__ h, const int* __restrict__ span, float* __restrict__ hg)
{
  int x = blockIdx.x;            // 0 .. 2*MROWS-1
  int sel = (x >= MROWS) ? 1 : 0;
  int r = x - sel * MROWS;       // 0..383
  int b = r / Kspan, k = r - b * Kspan;
  int idx = span[(b * Kspan + k) * 2 + sel];
  const float* src = h + ((size_t)b * Ldim + idx) * Ddim;
  float* dst = hg + (size_t)x * Ddim;
  for (int d = threadIdx.x; d < Ddim; d += 256) dst[d] = src[d];
}

// ---------------- split-bf16 GEMM: C = f(A_fp32 @ WT^T + bias), near-fp32 accuracy ----------
// A: [M][ldA] fp32 row-major.  WT(h/l): [N][ldW] bf16 (i.e. W transposed).  C: fp32 [M][ldC].
// BM=64, BN=128, BK=32; 256 threads, wave grid 2x2 (wave tile 32x64).
template<bool RELU>
__global__ __launch_bounds__(256) void gemm_split(
    const float* __restrict__ A, int ldA,
    const unsigned short* __restrict__ WTh, const unsigned short* __restrict__ WTl, int ldW,
    const float* __restrict__ bias,
    float* __restrict__ C, int ldC, int K)
{
  constexpr int SR = 40;  // padded row stride (shorts): 80B, kills 8-way bank conflict
  __shared__ __align__(16) unsigned short Ah[64 * SR], Al[64 * SR];
  __shared__ __align__(16) unsigned short Bh[128 * SR], Bl[128 * SR];
  int m0 = blockIdx.y * 64, n0 = blockIdx.x * 128;
  int t = threadIdx.x, lane = t & 63, wid = t >> 6;
  int wm = wid >> 1, wn = wid & 1;
  int lr = lane & 15, lk = (lane >> 4) * 8;
  f32x4 acc[2][4] = {};
  int ar = t >> 2, akq = t & 3;
  for (int k0 = 0; k0 < K; k0 += 32){
    { // stage A tile 64x32 fp32 -> hi/lo bf16
      const float* s = A + (size_t)(m0 + ar) * ldA + k0 + akq * 8;
      f32x4 x0 = *(const f32x4*)s, x1 = *(const f32x4*)(s + 4);
      ushort8v vh, vl;
      for (int e = 0; e < 4; e++){ float x = x0[e]; unsigned short hh = f2bf(x); vh[e] = hh; vl[e] = f2bf(x - bf2f(hh)); }
      for (int e = 0; e < 4; e++){ float x = x1[e]; unsigned short hh = f2bf(x); vh[e+4] = hh; vl[e+4] = f2bf(x - bf2f(hh)); }
      *(ushort8v*)&Ah[ar * SR + akq * 8] = vh;
      *(ushort8v*)&Al[ar * SR + akq * 8] = vl;
    }
    for (int p = 0; p < 2; p++){ // stage B tile 128x32 (pre-split planes)
      int idx = p * 256 + t; int n = idx >> 2, kq = idx & 3;
      size_t go = (size_t)(n0 + n) * ldW + k0 + kq * 8;
      *(ushort8v*)&Bh[n * SR + kq * 8] = *(const ushort8v*)(WTh + go);
      *(ushort8v*)&Bl[n * SR + kq * 8] = *(const ushort8v*)(WTl + go);
    }
    __syncthreads();
    bf16x8 ah[2], al2[2], bh[4], bl[4];
    for (int f = 0; f < 2; f++){ int o = (wm * 32 + f * 16 + lr) * SR + lk; ah[f] = *(const bf16x8*)&Ah[o]; al2[f] = *(const bf16x8*)&Al[o]; }
    for (int g = 0; g < 4; g++){ int o = (wn * 64 + g * 16 + lr) * SR + lk; bh[g] = *(const bf16x8*)&Bh[o]; bl[g] = *(const bf16x8*)&Bl[o]; }
    for (int f = 0; f < 2; f++)
      for (int g = 0; g < 4; g++){
        acc[f][g] = __builtin_amdgcn_mfma_f32_16x16x32_bf16(ah[f],  bh[g], acc[f][g], 0, 0, 0);
        acc[f][g] = __builtin_amdgcn_mfma_f32_16x16x32_bf16(ah[f],  bl[g], acc[f][g], 0, 0, 0);
        acc[f][g] = __builtin_amdgcn_mfma_f32_16x16x32_bf16(al2[f], bh[g], acc[f][g], 0, 0, 0);
      }
    __syncthreads();
  }
  int rr = (lane >> 4) * 4;
  for (int f = 0; f < 2; f++){
    int gm = m0 + wm * 32 + f * 16 + rr;
    for (int g = 0; g < 4; g++){
      int gn = n0 + wn * 64 + g * 16 + (lane & 15);
      float bv = bias ? bias[gn] : 0.f;
      for (int r2 = 0; r2 < 4; r2++){
        float v = acc[f][g][r2] + bv;
        if (RELU) v = fmaxf(v, 0.f);
        C[(size_t)(gm + r2) * ldC + gn] = v;
      }
    }
  }
}

// ---------------- fused pair GEMM: out[b, p(i,j), :] = relu(U[b,i]+V[b,j]) @ ro_w2 + b2 -----
// One block per (b, i, half). M-tile = 96 j-rows, N-tile = 384 cols, K = 3072, BK = 64.
// 512 threads, 8 waves (2 x 4): wave tile 48 x 96.
__global__ __launch_bounds__(512) void pair_gemm(
    const float* __restrict__ U,   // [Bdim*Kspan][Hdim], ro_b1 folded in
    const float* __restrict__ V,   // [Bdim*Kspan][Hdim]
    const unsigned short* __restrict__ W2T, // [Ddim][Hdim] bf16 (ro_w2 transposed)
    const float* __restrict__ b2,  // [Ddim]
    float* __restrict__ out)       // [Bdim*Pdim][Ddim]
{
  constexpr int SR = 72;  // padded row stride (shorts) for BK=64: 144B, conflict-free
  __shared__ __align__(16) unsigned short As[96 * SR];
  __shared__ __align__(16) unsigned short Bs[384 * SR];
  int bi = blockIdx.x >> 1, half = blockIdx.x & 1;
  int b = bi / Kspan, i = bi - b * Kspan;
  const float* Urow  = U + ((size_t)b * Kspan + i) * Hdim;
  const float* Vbase = V + (size_t)b * Kspan * Hdim;
  int t = threadIdx.x, lane = t & 63, wid = t >> 6;
  int wm = wid >> 2, wn = wid & 3;
  int lr = lane & 15, lk = (lane >> 4) * 8;
  f32x4 acc[3][6] = {};
  for (int k0 = 0; k0 < Hdim; k0 += 64){
    // stage A: 96 rows x 64, A[j][k] = relu(U[i][k]+V[j][k]) -> bf16
    for (int idx = t; idx < 768; idx += 512){
      int row = idx >> 3, kq = idx & 7;
      int kb = k0 + kq * 8;
      f32x4 u0 = *(const f32x4*)(Urow + kb);
      f32x4 u1 = *(const f32x4*)(Urow + kb + 4);
      const float* vr = Vbase + (size_t)row * Hdim + kb;
      f32x4 v0 = *(const f32x4*)vr;
      f32x4 v1 = *(const f32x4*)(vr + 4);
      ushort8v pk;
      for (int e = 0; e < 4; e++) pk[e]     = f2bf(fmaxf(u0[e] + v0[e], 0.f));
      for (int e = 0; e < 4; e++) pk[e + 4] = f2bf(fmaxf(u1[e] + v1[e], 0.f));
      *(ushort8v*)&As[row * SR + kq * 8] = pk;
    }
    // stage B: 384 rows x 64 from W2T
    for (int idx = t; idx < 3072; idx += 512){
      int n = idx >> 3, kq = idx & 7;
      ushort8v v = *(const ushort8v*)(W2T + (size_t)(half * 384 + n) * Hdim + k0 + kq * 8);
      *(ushort8v*)&Bs[n * SR + kq * 8] = v;
    }
    __syncthreads();
    for (int kh = 0; kh < 2; kh++){
      bf16x8 a[3], bb[6];
      for (int f = 0; f < 3; f++) a[f]  = *(const bf16x8*)&As[(wm * 48 + f * 16 + lr) * SR + kh * 32 + lk];
      for (int g = 0; g < 6; g++) bb[g] = *(const bf16x8*)&Bs[(wn * 96 + g * 16 + lr) * SR + kh * 32 + lk];
      for (int f = 0; f < 3; f++)
        for (int g = 0; g < 6; g++)
          acc[f][g] = __builtin_amdgcn_mfma_f32_16x16x32_bf16(a[f], bb[g], acc[f][g], 0, 0, 0);
    }
    __syncthreads();
  }
  // epilogue: row j -> pair p = i*95 + j - (j>i); skip j==i
  size_t outB = (size_t)b * Pdim;
  int rr = (lane >> 4) * 4;
  for (int f = 0; f < 3; f++){
    int jbase = wm * 48 + f * 16 + rr;
    for (int r2 = 0; r2 < 4; r2++){
      int j = jbase + r2;
      if (j == i) continue;
      int p = i * 95 + j - (j > i ? 1 : 0);
      float* orow = out + (outB + p) * Ddim + half * 384;
      for (int g = 0; g < 6; g++){
        int gn = wn * 96 + g * 16 + (lane & 15);
        orow[gn] = acc[f][g][r2] + b2[half * 384 + gn];
      }
    }
  }
}

// ---------------- host launch ----------------
extern "C" void kernel_launch(void* const* d_in, const int* in_sizes, int n_in,
                              void* d_out, int out_size, void* d_ws, size_t ws_size,
                              hipStream_t stream)
{
  (void)in_sizes; (void)n_in; (void)out_size;
  const float* h     = (const float*)d_in[0];
  const int*   span  = (const int*)d_in[1];
  const float* ps_w1 = (const float*)d_in[2];
  const float* ps_b1 = (const float*)d_in[3];
  const float* ps_w2 = (const float*)d_in[4];
  const float* ps_b2 = (const float*)d_in[5];
  const float* pe_w1 = (const float*)d_in[6];
  const float* pe_b1 = (const float*)d_in[7];
  const float* pe_w2 = (const float*)d_in[8];
  const float* pe_b2 = (const float*)d_in[9];
  const float* so_w1 = (const float*)d_in[10];
  const float* so_b1 = (const float*)d_in[11];
  const float* so_w2 = (const float*)d_in[12];
  const float* so_b2 = (const float*)d_in[13];
  const float* ro_w1 = (const float*)d_in[14];
  const float* ro_b1 = (const float*)d_in[15];
  const float* ro_w2 = (const float*)d_in[16];
  const float* ro_b2 = (const float*)d_in[17];

  char* ws = (char*)d_ws;
  size_t off = 0;
  auto alloc_us = [&](size_t n)->unsigned short*{
    unsigned short* p = (unsigned short*)(ws + off);
    off += ((n * 2 + 255) & ~(size_t)255);
    return p;
  };
  auto alloc_f = [&](size_t n)->float*{
    float* p = (float*)(ws + off);
    off += ((n * 4 + 255) & ~(size_t)255);
    return p;
  };

  // bf16 weight planes (transposed): hi + lo for split GEMMs, single for ro_w2
  unsigned short* ps1h = alloc_us((size_t)Hdim * Ddim); unsigned short* ps1l = alloc_us((size_t)Hdim * Ddim);
  unsigned short* ps2h = alloc_us((size_t)Ddim * Hdim); unsigned short* ps2l = alloc_us((size_t)Ddim * Hdim);
  unsigned short* pe1h = alloc_us((size_t)Hdim * Ddim); unsigned short* pe1l = alloc_us((size_t)Hdim * Ddim);
  unsigned short* pe2h = alloc_us((size_t)Ddim * Hdim); unsigned short* pe2l = alloc_us((size_t)Ddim * Hdim);
  unsigned short* so1h = alloc_us((size_t)Hdim * 2 * Ddim); unsigned short* so1l = alloc_us((size_t)Hdim * 2 * Ddim);
  unsigned short* so2h = alloc_us((size_t)Ddim * Hdim); unsigned short* so2l = alloc_us((size_t)Ddim * Hdim);
  unsigned short* ro1h = alloc_us((size_t)Hdim * 2 * Ddim); unsigned short* ro1l = alloc_us((size_t)Hdim * 2 * Ddim);
  unsigned short* ro2T = alloc_us((size_t)Ddim * Hdim);
  // fp32 intermediates
  float* hg     = alloc_f((size_t)2 * MROWS * Ddim);
  float* mid_s  = alloc_f((size_t)MROWS * Hdim);
  float* mid_e  = alloc_f((size_t)MROWS * Hdim);
  float* cat    = alloc_f((size_t)MROWS * 2 * Ddim);
  float* entity = alloc_f((size_t)MROWS * Ddim);
  float* Ubuf   = alloc_f((size_t)MROWS * Hdim);
  float* Vbuf   = alloc_f((size_t)MROWS * Hdim);
  if (off > ws_size) return;  // insufficient workspace -> clean validation failure

  dim3 tb(256);
  // transposes: W[K][N] -> WT[N][K]
  transpose_split<<<dim3(Hdim/64, Ddim/64), tb, 0, stream>>>(ps_w1, ps1h, ps1l, Ddim, Hdim);
  transpose_split<<<dim3(Ddim/64, Hdim/64), tb, 0, stream>>>(ps_w2, ps2h, ps2l, Hdim, Ddim);
  transpose_split<<<dim3(Hdim/64, Ddim/64), tb, 0, stream>>>(pe_w1, pe1h, pe1l, Ddim, Hdim);
  transpose_split<<<dim3(Ddim/64, Hdim/64), tb, 0, stream>>>(pe_w2, pe2h, pe2l, Hdim, Ddim);
  transpose_split<<<dim3(Hdim/64, (2*Ddim)/64), tb, 0, stream>>>(so_w1, so1h, so1l, 2*Ddim, Hdim);
  transpose_split<<<dim3(Ddim/64, Hdim/64), tb, 0, stream>>>(so_w2, so2h, so2l, Hdim, Ddim);
  transpose_split<<<dim3(Hdim/64, (2*Ddim)/64), tb, 0, stream>>>(ro_w1, ro1h, ro1l, 2*Ddim, Hdim);
  transpose_cvt1 <<<dim3(Ddim/64, Hdim/64), tb, 0, stream>>>(ro_w2, ro2T, Hdim, Ddim);

  gather_rows<<<2 * MROWS, tb, 0, stream>>>(h, span, hg);

  // start/end projections on gathered rows (M=384)
  gemm_split<true ><<<dim3(Hdim/128, MROWS/64), tb, 0, stream>>>(hg,                 Ddim, ps1h, ps1l, Ddim, ps_b1, mid_s, Hdim, Ddim);
  gemm_split<true ><<<dim3(Hdim/128, MROWS/64), tb, 0, stream>>>(hg + (size_t)MROWS*Ddim, Ddim, pe1h, pe1l, Ddim, pe_b1, mid_e, Hdim, Ddim);
  // second linear + outer relu, written straight into concat halves
  gemm_split<true ><<<dim3(Ddim/128, MROWS/64), tb, 0, stream>>>(mid_s, Hdim, ps2h, ps2l, Hdim, ps_b2, cat,        2*Ddim, Hdim);
  gemm_split<true ><<<dim3(Ddim/128, MROWS/64), tb, 0, stream>>>(mid_e, Hdim, pe2h, pe2l, Hdim, pe_b2, cat + Ddim, 2*Ddim, Hdim);
  // entity projection
  gemm_split<true ><<<dim3(Hdim/128, MROWS/64), tb, 0, stream>>>(cat,   2*Ddim, so1h, so1l, 2*Ddim, so_b1, mid_s,  Hdim, 2*Ddim);
  gemm_split<false><<<dim3(Ddim/128, MROWS/64), tb, 0, stream>>>(mid_s, Hdim,   so2h, so2l, Hdim,   so_b2, entity, Ddim, Hdim);
  // U = entity @ ro_w1_top + ro_b1 ; V = entity @ ro_w1_bot
  gemm_split<false><<<dim3(Hdim/128, MROWS/64), tb, 0, stream>>>(entity, Ddim, ro1h,        ro1l,        2*Ddim, ro_b1,  Ubuf, Hdim, Ddim);
  gemm_split<false><<<dim3(Hdim/128, MROWS/64), tb, 0, stream>>>(entity, Ddim, ro1h + Ddim, ro1l + Ddim, 2*Ddim, nullptr, Vbuf, Hdim, Ddim);

  // fused pair GEMM
  pair_gemm<<<Bdim * Kspan * 2, 512, 0, stream>>>(Ubuf, Vbuf, ro2T, ro_b2, (float*)d_out);
}

// Round 2
// 538.829 us; speedup vs baseline: 1.5544x; 1.5544x over previous
//
#include <hip/hip_runtime.h>
#include <hip/hip_bf16.h>

// ---- problem dims (fixed) ----
#define Bdim 4
#define Ldim 512
#define Ddim 768
#define Kspan 96
#define Hdim 3072
#define Pdim 9120      // Kspan*(Kspan-1)
#define MROWS 384      // Bdim*Kspan
#define NT 48          // Hdim / 64

typedef __bf16 bf16x8 __attribute__((ext_vector_type(8)));
typedef float f32x4 __attribute__((ext_vector_type(4)));
typedef float f32x16 __attribute__((ext_vector_type(16)));
typedef unsigned short ushort8v __attribute__((ext_vector_type(8)));

static __device__ __forceinline__ unsigned short f2bf(float x){
  return __builtin_bit_cast(unsigned short, (__bf16)x);
}
static __device__ __forceinline__ float bf2f(unsigned short u){
  return (float)__builtin_bit_cast(__bf16, u);
}

// ---------------- transpose + convert: W[K][N] fp32 -> WT[N][K] bf16 hi(+lo) ----------------
__global__ __launch_bounds__(256) void transpose_split(
    const float* __restrict__ W, unsigned short* __restrict__ WTh,
    unsigned short* __restrict__ WTl, int K, int N)
{
  __shared__ float tile[64][65];
  int k0 = blockIdx.y * 64, n0 = blockIdx.x * 64;
  int c = threadIdx.x & 63, r0 = threadIdx.x >> 6;
  for (int p = 0; p < 16; p++){
    int r = r0 + p * 4;
    tile[c][r] = W[(size_t)(k0 + r) * N + n0 + c];
  }
  __syncthreads();
  for (int p = 0; p < 16; p++){
    int n = r0 + p * 4;
    float x = tile[n][c];
    unsigned short h = f2bf(x);
    size_t o = (size_t)(n0 + n) * K + k0 + c;
    WTh[o] = h;
    WTl[o] = f2bf(x - bf2f(h));
  }
}

// transpose + convert single-plane, with per-row XOR-swizzle of 16B granules inside each
// 64-element k-block: phys granule = logical granule ^ (nrow & 7).  This is the inverse
// permutation needed so that a LINEAR global_load_lds copy lands a swizzled LDS tile (T21).
__global__ __launch_bounds__(256) void transpose_cvt_swz(
    const float* __restrict__ W, unsigned short* __restrict__ WT, int K, int N)
{
  __shared__ float tile[64][65];
  int k0 = blockIdx.y * 64, n0 = blockIdx.x * 64;
  int c = threadIdx.x & 63, r0 = threadIdx.x >> 6;
  for (int p = 0; p < 16; p++){
    int r = r0 + p * 4;
    tile[c][r] = W[(size_t)(k0 + r) * N + n0 + c];
  }
  __syncthreads();
  for (int p = 0; p < 16; p++){
    int n = r0 + p * 4;
    int nrow = n0 + n;
    int kk = k0 + c;
    int gq = (kk >> 3) & 7, e = kk & 7;
    int kph = (kk & ~63) | ((gq ^ (nrow & 7)) << 3) | e;
    WT[(size_t)nrow * K + kph] = f2bf(tile[n][c]);
  }
}

// ---------------- gather h rows at span indices (fp32 copy) ----------------
__global__ __launch_bounds__(256) void gather_rows(
    const float* __restrict__ h, const int* __restrict__ span, float* __restrict__ hg)
{
  int x = blockIdx.x;            // 0 .. 2*MROWS-1
  int sel = (x >= MROWS) ? 1 : 0;
  int r = x - sel * MROWS;
  int b = r / Kspan, k = r - b * Kspan;
  int idx = span[(b * Kspan + k) * 2 + sel];
  const float* src = h + ((size_t)b * Ldim + idx) * Ddim;
  float* dst = hg + (size_t)x * Ddim;
  for (int d = threadIdx.x; d < Ddim; d += 256) dst[d] = src[d];
}

// ---------------- split-bf16 GEMM (multi-job + optional split-K) ------------------------
// MODE 0: store relu(acc+bias); MODE 1: store acc+bias (bias may be null);
// MODE 2: store raw partial to J.C + s*csz (split-K).
struct GJob {
  const float* A;
  const unsigned short* Wh;
  const unsigned short* Wl;
  const float* bias;
  float* C;
};

template<int MODE, int SPLIT>
__global__ __launch_bounds__(256) void gemm_ms(
    GJob j0, GJob j1, int ldA, int ldW, int ldC, int kLen, size_t csz)
{
  constexpr int SR = 40;
  __shared__ __align__(16) unsigned short Ah[64 * SR], Al[64 * SR];
  __shared__ __align__(16) unsigned short Bh[128 * SR], Bl[128 * SR];
  int zj, s;
  if (SPLIT == 1){ zj = blockIdx.z; s = 0; }
  else { zj = blockIdx.z / SPLIT; s = blockIdx.z % SPLIT; }
  const GJob J = zj ? j1 : j0;
  int kBegin = s * kLen;
  float* Cptr = (MODE == 2) ? (J.C + (size_t)s * csz) : J.C;

  int m0 = blockIdx.y * 64, n0 = blockIdx.x * 128;
  int t = threadIdx.x, lane = t & 63, wid = t >> 6;
  int wm = wid >> 1, wn = wid & 1;
  int lr = lane & 15, lk = (lane >> 4) * 8;
  f32x4 acc[2][4] = {};
  int ar = t >> 2, akq = t & 3;
  for (int k0 = 0; k0 < kLen; k0 += 32){
    { // stage A tile 64x32 fp32 -> hi/lo bf16
      const float* sp = J.A + (size_t)(m0 + ar) * ldA + kBegin + k0 + akq * 8;
      f32x4 x0 = *(const f32x4*)sp, x1 = *(const f32x4*)(sp + 4);
      ushort8v vh, vl;
      for (int e = 0; e < 4; e++){ float x = x0[e]; unsigned short hh = f2bf(x); vh[e] = hh; vl[e] = f2bf(x - bf2f(hh)); }
      for (int e = 0; e < 4; e++){ float x = x1[e]; unsigned short hh = f2bf(x); vh[e+4] = hh; vl[e+4] = f2bf(x - bf2f(hh)); }
      *(ushort8v*)&Ah[ar * SR + akq * 8] = vh;
      *(ushort8v*)&Al[ar * SR + akq * 8] = vl;
    }
    for (int p = 0; p < 2; p++){ // stage B tile 128x32
      int idx = p * 256 + t; int n = idx >> 2, kq = idx & 3;
      size_t go = (size_t)(n0 + n) * ldW + kBegin + k0 + kq * 8;
      *(ushort8v*)&Bh[n * SR + kq * 8] = *(const ushort8v*)(J.Wh + go);
      *(ushort8v*)&Bl[n * SR + kq * 8] = *(const ushort8v*)(J.Wl + go);
    }
    __syncthreads();
    bf16x8 ah[2], al2[2], bh[4], bl[4];
    for (int f = 0; f < 2; f++){ int o = (wm * 32 + f * 16 + lr) * SR + lk; ah[f] = *(const bf16x8*)&Ah[o]; al2[f] = *(const bf16x8*)&Al[o]; }
    for (int g = 0; g < 4; g++){ int o = (wn * 64 + g * 16 + lr) * SR + lk; bh[g] = *(const bf16x8*)&Bh[o]; bl[g] = *(const bf16x8*)&Bl[o]; }
    for (int f = 0; f < 2; f++)
      for (int g = 0; g < 4; g++){
        acc[f][g] = __builtin_amdgcn_mfma_f32_16x16x32_bf16(ah[f],  bh[g], acc[f][g], 0, 0, 0);
        acc[f][g] = __builtin_amdgcn_mfma_f32_16x16x32_bf16(ah[f],  bl[g], acc[f][g], 0, 0, 0);
        acc[f][g] = __builtin_amdgcn_mfma_f32_16x16x32_bf16(al2[f], bh[g], acc[f][g], 0, 0, 0);
      }
    __syncthreads();
  }
  int rr = (lane >> 4) * 4;
  for (int f = 0; f < 2; f++){
    int gm = m0 + wm * 32 + f * 16 + rr;
    for (int g = 0; g < 4; g++){
      int gn = n0 + wn * 64 + g * 16 + (lane & 15);
      float bv = (MODE != 2 && J.bias) ? J.bias[gn] : 0.f;
      for (int r2 = 0; r2 < 4; r2++){
        float v = acc[f][g][r2] + bv;
        if (MODE == 0) v = fmaxf(v, 0.f);
        Cptr[(size_t)(gm + r2) * ldC + gn] = v;
      }
    }
  }
}

// ---------------- split-K partial reduce: out[r][z*768+c] = (relu?)(sum_s P + bias_z) ----
template<bool RELU>
__global__ __launch_bounds__(256) void reduce_part(
    const float* __restrict__ P, int S,
    const float* __restrict__ bias0, const float* __restrict__ bias1,
    float* __restrict__ outp, int zCount, int ldOut)
{
  const int MN = MROWS * Ddim;
  int idx4 = blockIdx.x * 256 + threadIdx.x;
  int flat = idx4 * 4;
  if (flat >= MN * zCount) return;
  int z = flat / MN; int rem = flat - z * MN;
  int r = rem / Ddim; int c = rem - r * Ddim;
  const float* base = P + (size_t)z * S * MN + rem;
  f32x4 sv = *(const f32x4*)base;
  for (int ss = 1; ss < S; ss++){ f32x4 v = *(const f32x4*)(base + (size_t)ss * MN); sv += v; }
  const float* bp = z ? bias1 : bias0;
  f32x4 bv = *(const f32x4*)(bp + c);
  sv += bv;
  if (RELU) for (int e = 0; e < 4; e++) sv[e] = fmaxf(sv[e], 0.f);
  *(f32x4*)(outp + (size_t)r * ldOut + z * Ddim + c) = sv;
}

// ---------------- fused pair GEMM v2 --------------------------------------------------
// out[b, p(i,j), half*384+c] = relu(U[b,i]+V[b,j]) @ ro_w2 + b2
// Grid 768 = 8 (xcd: half,b) x 96 (i).  256 threads / 4 waves, wave tile 96x96,
// mfma_f32_32x32x16_bf16, 3x3 frags.  BK=64.
// Bs double-buffered via global_load_lds from pre-swizzled W2Ts (T21);
// As double-buffered reg->ds_write (XOR-swizzled).  ONE barrier per K-step.
__global__ __launch_bounds__(256) void pair_gemm2(
    const float* __restrict__ U,   // [MROWS][Hdim] fp32, ro_b1 folded
    const float* __restrict__ V,   // [MROWS][Hdim] fp32
    const unsigned short* __restrict__ W2Ts, // [Ddim][Hdim] bf16, pre-swizzled granules
    const float* __restrict__ b2,  // [Ddim]
    float* __restrict__ out)       // [Bdim*Pdim][Ddim]
{
  __shared__ __align__(16) unsigned short Bs[2][384 * 64]; // 96 KiB
  __shared__ __align__(16) unsigned short As[2][96 * 64];  // 24 KiB

  int x = blockIdx.x;
  int xcd = x & 7, i = x >> 3;      // i in [0,96)
  int half = xcd >> 2;
  int b = xcd & 3;

  const float* Urow = U + ((size_t)b * Kspan + i) * Hdim;
  const float* Vb   = V + (size_t)b * Kspan * Hdim;
  const unsigned short* Wp = W2Ts + (size_t)half * 384 * Hdim;

  int t = threadIdx.x, lane = t & 63, w = t >> 6;
  int kq = t & 7, r0a = t >> 3;     // A item: rows r0a + 32*it, granule kq

  float ureg[8];
  float vreg[3][8];
  f32x16 acc[3][3] = {};

  auto issueB = [&](int tt, int buf){
    const unsigned short* wkp = Wp + tt * 64;
    unsigned int* ldsbase = (unsigned int*)&Bs[buf][0];
    int c0 = w * 12;
    #pragma unroll
    for (int q = 0; q < 12; q++){
      int row = (c0 + q) * 8 + (lane >> 3);
      const unsigned short* src = wkp + (size_t)row * Hdim + (lane & 7) * 8;
      unsigned int* dst = ldsbase + ((c0 + q) * 256 + lane * 4);
      __builtin_amdgcn_global_load_lds(
          (const __attribute__((address_space(1))) unsigned int*)src,
          (__attribute__((address_space(3))) unsigned int*)dst, 16, 0, 0);
    }
  };
  auto issueA = [&](int tt){
    const float* up = Urow + tt * 64 + kq * 8;
    *(f32x4*)&ureg[0] = *(const f32x4*)up;
    *(f32x4*)&ureg[4] = *(const f32x4*)(up + 4);
    #pragma unroll
    for (int it = 0; it < 3; it++){
      const float* vp = Vb + (size_t)(r0a + 32 * it) * Hdim + tt * 64 + kq * 8;
      *(f32x4*)&vreg[it][0] = *(const f32x4*)vp;
      *(f32x4*)&vreg[it][4] = *(const f32x4*)(vp + 4);
    }
  };
  auto writeA = [&](int buf){
    #pragma unroll
    for (int it = 0; it < 3; it++){
      int r = r0a + 32 * it;
      ushort8v pk;
      #pragma unroll
      for (int e = 0; e < 8; e++) pk[e] = f2bf(fmaxf(ureg[e] + vreg[it][e], 0.f));
      *(ushort8v*)((char*)&As[buf][0] + r * 128 + ((kq ^ (r & 7)) * 16)) = pk;
    }
  };
  auto mfmaPhase = [&](int buf){
    #pragma unroll
    for (int kh = 0; kh < 4; kh++){
      int gg = kh * 2 + (lane >> 5);
      bf16x8 af[3], bfr[3];
      #pragma unroll
      for (int mf = 0; mf < 3; mf++){
        int r = mf * 32 + (lane & 31);
        af[mf] = *(const bf16x8*)((const char*)&As[buf][0] + r * 128 + ((gg ^ (r & 7)) * 16));
      }
      #pragma unroll
      for (int nf = 0; nf < 3; nf++){
        int n = w * 96 + nf * 32 + (lane & 31);
        bfr[nf] = *(const bf16x8*)((const char*)&Bs[buf][0] + n * 128 + ((gg ^ (n & 7)) * 16));
      }
      __builtin_amdgcn_s_setprio(1);
      #pragma unroll
      for (int mf = 0; mf < 3; mf++)
        #pragma unroll
        for (int nf = 0; nf < 3; nf++)
          acc[mf][nf] = __builtin_amdgcn_mfma_f32_32x32x16_bf16(af[mf], bfr[nf], acc[mf][nf], 0, 0, 0);
      __builtin_amdgcn_s_setprio(0);
    }
  };

  // prologue: stage tile 0
  issueB(0, 0);
  issueA(0);
  writeA(0);
  __syncthreads();   // implicit vmcnt(0): B DMA + A loads complete

  for (int tt = 0; tt < NT; tt++){
    int cur = tt & 1;
    if (tt + 1 < NT){ issueB(tt + 1, cur ^ 1); issueA(tt + 1); }
    mfmaPhase(cur);
    if (tt + 1 < NT) writeA(cur ^ 1);
    __syncthreads();
  }

  // epilogue
  size_t outB = (size_t)b * Pdim;
  int colbase = half * 384 + w * 96;
  float bc[3];
  #pragma unroll
  for (int nf = 0; nf < 3; nf++) bc[nf] = b2[colbase + nf * 32 + (lane & 31)];
  #pragma unroll
  for (int mf = 0; mf < 3; mf++){
    #pragma unroll
    for (int reg = 0; reg < 16; reg++){
      int j = mf * 32 + (reg & 3) + 8 * (reg >> 2) + 4 * (lane >> 5);
      if (j == i) continue;
      int p = i * 95 + j - (j > i ? 1 : 0);
      float* orow = out + (outB + p) * Ddim + colbase;
      #pragma unroll
      for (int nf = 0; nf < 3; nf++){
        int cn = nf * 32 + (lane & 31);
        orow[cn] = acc[mf][nf][reg] + bc[nf];
      }
    }
  }
}

// ---------------- host launch ----------------
extern "C" void kernel_launch(void* const* d_in, const int* in_sizes, int n_in,
                              void* d_out, int out_size, void* d_ws, size_t ws_size,
                              hipStream_t stream)
{
  (void)in_sizes; (void)n_in; (void)out_size;
  const float* h     = (const float*)d_in[0];
  const int*   span  = (const int*)d_in[1];
  const float* ps_w1 = (const float*)d_in[2];
  const float* ps_b1 = (const float*)d_in[3];
  const float* ps_w2 = (const float*)d_in[4];
  const float* ps_b2 = (const float*)d_in[5];
  const float* pe_w1 = (const float*)d_in[6];
  const float* pe_b1 = (const float*)d_in[7];
  const float* pe_w2 = (const float*)d_in[8];
  const float* pe_b2 = (const float*)d_in[9];
  const float* so_w1 = (const float*)d_in[10];
  const float* so_b1 = (const float*)d_in[11];
  const float* so_w2 = (const float*)d_in[12];
  const float* so_b2 = (const float*)d_in[13];
  const float* ro_w1 = (const float*)d_in[14];
  const float* ro_b1 = (const float*)d_in[15];
  const float* ro_w2 = (const float*)d_in[16];
  const float* ro_b2 = (const float*)d_in[17];

  char* ws = (char*)d_ws;
  size_t off = 0;
  auto alloc_us = [&](size_t n)->unsigned short*{
    unsigned short* p = (unsigned short*)(ws + off);
    off += ((n * 2 + 255) & ~(size_t)255);
    return p;
  };
  auto alloc_f = [&](size_t n)->float*{
    float* p = (float*)(ws + off);
    off += ((n * 4 + 255) & ~(size_t)255);
    return p;
  };

  unsigned short* ps1h = alloc_us((size_t)Hdim * Ddim); unsigned short* ps1l = alloc_us((size_t)Hdim * Ddim);
  unsigned short* ps2h = alloc_us((size_t)Ddim * Hdim); unsigned short* ps2l = alloc_us((size_t)Ddim * Hdim);
  unsigned short* pe1h = alloc_us((size_t)Hdim * Ddim); unsigned short* pe1l = alloc_us((size_t)Hdim * Ddim);
  unsigned short* pe2h = alloc_us((size_t)Ddim * Hdim); unsigned short* pe2l = alloc_us((size_t)Ddim * Hdim);
  unsigned short* so1h = alloc_us((size_t)Hdim * 2 * Ddim); unsigned short* so1l = alloc_us((size_t)Hdim * 2 * Ddim);
  unsigned short* so2h = alloc_us((size_t)Ddim * Hdim); unsigned short* so2l = alloc_us((size_t)Ddim * Hdim);
  unsigned short* ro1h = alloc_us((size_t)Hdim * 2 * Ddim); unsigned short* ro1l = alloc_us((size_t)Hdim * 2 * Ddim);
  unsigned short* ro2Ts = alloc_us((size_t)Ddim * Hdim);
  float* hg     = alloc_f((size_t)2 * MROWS * Ddim);
  float* mid_s  = alloc_f((size_t)MROWS * Hdim);
  float* mid_e  = alloc_f((size_t)MROWS * Hdim);
  float* cat    = alloc_f((size_t)MROWS * 2 * Ddim);
  float* entity = alloc_f((size_t)MROWS * Ddim);
  float* Ubuf   = alloc_f((size_t)MROWS * Hdim);
  float* Vbuf   = alloc_f((size_t)MROWS * Hdim);
  const size_t MN = (size_t)MROWS * Ddim;
  float* P2 = alloc_f(8 * MN);   // ps2/pe2 split-K partials
  float* P3 = alloc_f(4 * MN);   // so2 split-K partials
  if (off > ws_size) return;

  dim3 tb(256);
  transpose_split<<<dim3(Hdim/64, Ddim/64), tb, 0, stream>>>(ps_w1, ps1h, ps1l, Ddim, Hdim);
  transpose_split<<<dim3(Ddim/64, Hdim/64), tb, 0, stream>>>(ps_w2, ps2h, ps2l, Hdim, Ddim);
  transpose_split<<<dim3(Hdim/64, Ddim/64), tb, 0, stream>>>(pe_w1, pe1h, pe1l, Ddim, Hdim);
  transpose_split<<<dim3(Ddim/64, Hdim/64), tb, 0, stream>>>(pe_w2, pe2h, pe2l, Hdim, Ddim);
  transpose_split<<<dim3(Hdim/64, (2*Ddim)/64), tb, 0, stream>>>(so_w1, so1h, so1l, 2*Ddim, Hdim);
  transpose_split<<<dim3(Ddim/64, Hdim/64), tb, 0, stream>>>(so_w2, so2h, so2l, Hdim, Ddim);
  transpose_split<<<dim3(Hdim/64, (2*Ddim)/64), tb, 0, stream>>>(ro_w1, ro1h, ro1l, 2*Ddim, Hdim);
  transpose_cvt_swz<<<dim3(Ddim/64, Hdim/64), tb, 0, stream>>>(ro_w2, ro2Ts, Hdim, Ddim);

  gather_rows<<<2 * MROWS, tb, 0, stream>>>(h, span, hg);

  // L1: start/end first linear (merged), M=384 N=3072 K=768
  {
    GJob j0{hg,                      ps1h, ps1l, ps_b1, mid_s};
    GJob j1{hg + (size_t)MROWS*Ddim, pe1h, pe1l, pe_b1, mid_e};
    gemm_ms<0,1><<<dim3(Hdim/128, MROWS/64, 2), tb, 0, stream>>>(j0, j1, Ddim, Ddim, Hdim, Ddim, 0);
  }
  // L2: start/end second linear (merged, split-K=4) -> partials
  {
    GJob j0{mid_s, ps2h, ps2l, nullptr, P2};
    GJob j1{mid_e, pe2h, pe2l, nullptr, P2 + 4*MN};
    gemm_ms<2,4><<<dim3(Ddim/128, MROWS/64, 8), tb, 0, stream>>>(j0, j1, Hdim, Hdim, Ddim, Hdim/4, MN);
  }
  reduce_part<true><<<(2*(int)MN)/1024, tb, 0, stream>>>(P2, 4, ps_b2, pe_b2, cat, 2, 2*Ddim);
  // so1: M=384 N=3072 K=1536
  {
    GJob j0{cat, so1h, so1l, so_b1, mid_s};
    gemm_ms<0,1><<<dim3(Hdim/128, MROWS/64, 1), tb, 0, stream>>>(j0, j0, 2*Ddim, 2*Ddim, Hdim, 2*Ddim, 0);
  }
  // so2: split-K=4 -> partials (no relu on entity)
  {
    GJob j0{mid_s, so2h, so2l, nullptr, P3};
    gemm_ms<2,4><<<dim3(Ddim/128, MROWS/64, 4), tb, 0, stream>>>(j0, j0, Hdim, Hdim, Ddim, Hdim/4, MN);
  }
  reduce_part<false><<<((int)MN)/1024, tb, 0, stream>>>(P3, 4, so_b2, so_b2, entity, 1, Ddim);
  // U = entity @ ro_w1_top + ro_b1 ; V = entity @ ro_w1_bot (merged)
  {
    GJob j0{entity, ro1h,        ro1l,        ro_b1,   Ubuf};
    GJob j1{entity, ro1h + Ddim, ro1l + Ddim, nullptr, Vbuf};
    gemm_ms<1,1><<<dim3(Hdim/128, MROWS/64, 2), tb, 0, stream>>>(j0, j1, Ddim, 2*Ddim, Hdim, Ddim, 0);
  }

  // fused pair GEMM v2
  pair_gemm2<<<Bdim * Kspan * 2, tb, 0, stream>>>(Ubuf, Vbuf, ro2Ts, ro_b2, (float*)d_out);
}

// Round 3
// 531.056 us; speedup vs baseline: 1.5772x; 1.0146x over previous
//
#include <hip/hip_runtime.h>
#include <hip/hip_bf16.h>

// ---- problem dims (fixed) ----
#define Bdim 4
#define Ldim 512
#define Ddim 768
#define Kspan 96
#define Hdim 3072
#define Pdim 9120      // Kspan*(Kspan-1)
#define MROWS 384      // Bdim*Kspan
#define NKT 96         // Hdim / 32 (K-tiles for pair kernel)

typedef __bf16 bf16x8 __attribute__((ext_vector_type(8)));
typedef float f32x4 __attribute__((ext_vector_type(4)));
typedef float f32x16 __attribute__((ext_vector_type(16)));
typedef unsigned short ushort8v __attribute__((ext_vector_type(8)));
typedef unsigned short ushort4v __attribute__((ext_vector_type(4)));

static __device__ __forceinline__ unsigned short f2bf(float x){
  return __builtin_bit_cast(unsigned short, (__bf16)x);
}
static __device__ __forceinline__ float bf2f(unsigned short u){
  return (float)__builtin_bit_cast(__bf16, u);
}

// ---------------- transpose + convert: W[K][N] fp32 -> WT[N][K] bf16 hi(+lo) ----------------
__global__ __launch_bounds__(256) void transpose_split(
    const float* __restrict__ W, unsigned short* __restrict__ WTh,
    unsigned short* __restrict__ WTl, int K, int N)
{
  __shared__ float tile[64][65];
  int k0 = blockIdx.y * 64, n0 = blockIdx.x * 64;
  int c = threadIdx.x & 63, r0 = threadIdx.x >> 6;
  for (int p = 0; p < 16; p++){
    int r = r0 + p * 4;
    tile[c][r] = W[(size_t)(k0 + r) * N + n0 + c];
  }
  __syncthreads();
  for (int p = 0; p < 16; p++){
    int n = r0 + p * 4;
    float x = tile[n][c];
    unsigned short h = f2bf(x);
    size_t o = (size_t)(n0 + n) * K + k0 + c;
    WTh[o] = h;
    WTl[o] = f2bf(x - bf2f(h));
  }
}

// ---------------- pack ro_w2 [Hdim][Ddim] f32 -> W2P bf16 fragment tiles ----------------
// W2P tile (nq, kt): 96 rows (n') x 32 k bf16, 64B rows, st_16x32 pre-swizzled:
// phys short idx o in [0,3072): n' = o>>5, kl = (o&31) ^ ((n'&8)<<1).
__global__ __launch_bounds__(256) void pack_w2(
    const float* __restrict__ W, unsigned short* __restrict__ W2P)
{
  __shared__ float tile[32][97];
  int kt = blockIdx.x, nq = blockIdx.y, t = threadIdx.x;
  for (int q = 0; q < 12; q++){
    int flat = q * 256 + t;            // 0..3071
    int kl = flat / 96, n = flat - kl * 96;
    tile[kl][n] = W[(size_t)(kt * 32 + kl) * Ddim + nq * 96 + n];
  }
  __syncthreads();
  unsigned short* outp = W2P + ((size_t)(nq * 96 + kt)) * 3072;
  for (int q = 0; q < 12; q++){
    int o = q * 256 + t;
    int n = o >> 5, klx = o & 31;
    int kl = klx ^ ((n & 8) << 1);
    outp[o] = f2bf(tile[kl][n]);
  }
}

// ---------------- pack Vbuf f32 [MROWS][Hdim] -> Vp bf16 [(b*96+kt)][96 j][32 k] ---------
__global__ __launch_bounds__(256) void pack_v(
    const float* __restrict__ Vbuf, unsigned short* __restrict__ Vp)
{
  int kt = blockIdx.x, b = blockIdx.y, t = threadIdx.x;
  unsigned short* outp = Vp + ((size_t)(b * 96 + kt)) * 3072;
  for (int q = 0; q < 12; q++){
    int flat = q * 256 + t;
    int j = flat >> 5, kl = flat & 31;
    outp[flat] = f2bf(Vbuf[(size_t)(b * 96 + j) * Hdim + kt * 32 + kl]);
  }
}

// ---------------- gather h rows at span indices (fp32 copy) ----------------
__global__ __launch_bounds__(256) void gather_rows(
    const float* __restrict__ h, const int* __restrict__ span, float* __restrict__ hg)
{
  int x = blockIdx.x;            // 0 .. 2*MROWS-1
  int sel = (x >= MROWS) ? 1 : 0;
  int r = x - sel * MROWS;
  int b = r / Kspan, k = r - b * Kspan;
  int idx = span[(b * Kspan + k) * 2 + sel];
  const float* src = h + ((size_t)b * Ldim + idx) * Ddim;
  float* dst = hg + (size_t)x * Ddim;
  for (int d = threadIdx.x; d < Ddim; d += 256) dst[d] = src[d];
}

// ---------------- split-bf16 GEMM (multi-job + optional split-K) ------------------------
struct GJob {
  const float* A;
  const unsigned short* Wh;
  const unsigned short* Wl;
  const float* bias;
  float* C;
};

template<int MODE, int SPLIT>
__global__ __launch_bounds__(256) void gemm_ms(
    GJob j0, GJob j1, int ldA, int ldW, int ldC, int kLen, size_t csz)
{
  constexpr int SR = 40;
  __shared__ __align__(16) unsigned short Ah[64 * SR], Al[64 * SR];
  __shared__ __align__(16) unsigned short Bh[128 * SR], Bl[128 * SR];
  int zj, s;
  if (SPLIT == 1){ zj = blockIdx.z; s = 0; }
  else { zj = blockIdx.z / SPLIT; s = blockIdx.z % SPLIT; }
  const GJob J = zj ? j1 : j0;
  int kBegin = s * kLen;
  float* Cptr = (MODE == 2) ? (J.C + (size_t)s * csz) : J.C;

  int m0 = blockIdx.y * 64, n0 = blockIdx.x * 128;
  int t = threadIdx.x, lane = t & 63, wid = t >> 6;
  int wm = wid >> 1, wn = wid & 1;
  int lr = lane & 15, lk = (lane >> 4) * 8;
  f32x4 acc[2][4] = {};
  int ar = t >> 2, akq = t & 3;
  for (int k0 = 0; k0 < kLen; k0 += 32){
    {
      const float* sp = J.A + (size_t)(m0 + ar) * ldA + kBegin + k0 + akq * 8;
      f32x4 x0 = *(const f32x4*)sp, x1 = *(const f32x4*)(sp + 4);
      ushort8v vh, vl;
      for (int e = 0; e < 4; e++){ float x = x0[e]; unsigned short hh = f2bf(x); vh[e] = hh; vl[e] = f2bf(x - bf2f(hh)); }
      for (int e = 0; e < 4; e++){ float x = x1[e]; unsigned short hh = f2bf(x); vh[e+4] = hh; vl[e+4] = f2bf(x - bf2f(hh)); }
      *(ushort8v*)&Ah[ar * SR + akq * 8] = vh;
      *(ushort8v*)&Al[ar * SR + akq * 8] = vl;
    }
    for (int p = 0; p < 2; p++){
      int idx = p * 256 + t; int n = idx >> 2, kq = idx & 3;
      size_t go = (size_t)(n0 + n) * ldW + kBegin + k0 + kq * 8;
      *(ushort8v*)&Bh[n * SR + kq * 8] = *(const ushort8v*)(J.Wh + go);
      *(ushort8v*)&Bl[n * SR + kq * 8] = *(const ushort8v*)(J.Wl + go);
    }
    __syncthreads();
    bf16x8 ah[2], al2[2], bh[4], bl[4];
    for (int f = 0; f < 2; f++){ int o = (wm * 32 + f * 16 + lr) * SR + lk; ah[f] = *(const bf16x8*)&Ah[o]; al2[f] = *(const bf16x8*)&Al[o]; }
    for (int g = 0; g < 4; g++){ int o = (wn * 64 + g * 16 + lr) * SR + lk; bh[g] = *(const bf16x8*)&Bh[o]; bl[g] = *(const bf16x8*)&Bl[o]; }
    for (int f = 0; f < 2; f++)
      for (int g = 0; g < 4; g++){
        acc[f][g] = __builtin_amdgcn_mfma_f32_16x16x32_bf16(ah[f],  bh[g], acc[f][g], 0, 0, 0);
        acc[f][g] = __builtin_amdgcn_mfma_f32_16x16x32_bf16(ah[f],  bl[g], acc[f][g], 0, 0, 0);
        acc[f][g] = __builtin_amdgcn_mfma_f32_16x16x32_bf16(al2[f], bh[g], acc[f][g], 0, 0, 0);
      }
    __syncthreads();
  }
  int rr = (lane >> 4) * 4;
  for (int f = 0; f < 2; f++){
    int gm = m0 + wm * 32 + f * 16 + rr;
    for (int g = 0; g < 4; g++){
      int gn = n0 + wn * 64 + g * 16 + (lane & 15);
      float bv = (MODE != 2 && J.bias) ? J.bias[gn] : 0.f;
      for (int r2 = 0; r2 < 4; r2++){
        float v = acc[f][g][r2] + bv;
        if (MODE == 0) v = fmaxf(v, 0.f);
        Cptr[(size_t)(gm + r2) * ldC + gn] = v;
      }
    }
  }
}

// ---------------- split-K partial reduce ----------------
template<bool RELU>
__global__ __launch_bounds__(256) void reduce_part(
    const float* __restrict__ P, int S,
    const float* __restrict__ bias0, const float* __restrict__ bias1,
    float* __restrict__ outp, int zCount, int ldOut)
{
  const int MN = MROWS * Ddim;
  int idx4 = blockIdx.x * 256 + threadIdx.x;
  int flat = idx4 * 4;
  if (flat >= MN * zCount) return;
  int z = flat / MN; int rem = flat - z * MN;
  int r = rem / Ddim; int c = rem - r * Ddim;
  const float* base = P + (size_t)z * S * MN + rem;
  f32x4 sv = *(const f32x4*)base;
  for (int ss = 1; ss < S; ss++){ f32x4 v = *(const f32x4*)(base + (size_t)ss * MN); sv += v; }
  const float* bp = z ? bias1 : bias0;
  f32x4 bv = *(const f32x4*)(bp + c);
  sv += bv;
  if (RELU) for (int e = 0; e < 4; e++) sv[e] = fmaxf(sv[e], 0.f);
  *(f32x4*)(outp + (size_t)r * ldOut + z * Ddim + c) = sv;
}

// ---------------- fused pair GEMM v3 --------------------------------------------------
// Block = (nq = x&7, b, iq): M = 384 rows (4 i's x 96 j), N = 96 cols, K = 3072 (BK=32).
// 4 waves, wave w owns i = iq*4+w, wave tile 96x96, mfma_f32_32x32x16, acc 3x3 f32x16.
// Bs via global_load_lds from pre-swizzled W2P (T21); A built in regs from packed Vp + U,
// ds_written st_16x32-swizzled.  Double-buffered, ONE barrier per K-step.
__global__ __launch_bounds__(256, 2) void pair_gemm3(
    const float* __restrict__ U,            // [MROWS][Hdim] f32, ro_b1 folded
    const unsigned short* __restrict__ Vp,  // packed bf16 per (b,kt): [96 j][32 k]
    const unsigned short* __restrict__ W2P, // packed bf16 per (nq,kt): swizzled [96 n][32 k]
    const float* __restrict__ b2,           // [Ddim]
    float* __restrict__ out)                // [Bdim*Pdim][Ddim]
{
  __shared__ __align__(16) unsigned short As[2][384 * 32]; // 2 x 24 KiB, 64B rows, swizzled
  __shared__ __align__(16) unsigned short Bs[2][96 * 32];  // 2 x 6 KiB, swizzled

  int x = blockIdx.x;
  int nq = x & 7;            // one nq per XCD -> B panel L2-resident
  int l = x >> 3;            // 0..95
  int b = l / 24;
  int iq = l - b * 24;       // 0..23

  int t = threadIdx.x, lane = t & 63, w = t >> 6;
  int kq = t & 7, jb = t >> 3;       // A-build coords: fixed k-granule, row group

  ushort4v vld[3];
  f32x4 uld[4];
  f32x16 acc[3][3] = {};

  auto issueB = [&](int kt, int buf){
    const unsigned short* tb = W2P + ((size_t)(nq * 96 + kt)) * 3072;
    #pragma unroll
    for (int s2 = 0; s2 < 2; s2++){
      int seg = w + s2 * 4;
      if (seg < 6){
        const unsigned short* src = tb + seg * 512 + lane * 8;
        unsigned int* dst = (unsigned int*)&Bs[buf][seg * 512 + lane * 8];
        __builtin_amdgcn_global_load_lds(
            (const __attribute__((address_space(1))) unsigned int*)src,
            (__attribute__((address_space(3))) unsigned int*)dst, 16, 0, 0);
      }
    }
  };
  auto issueUV = [&](int kt){
    const unsigned short* vb = Vp + ((size_t)(b * 96 + kt)) * 3072 + kq * 4;
    #pragma unroll
    for (int q = 0; q < 3; q++)
      vld[q] = *(const ushort4v*)(vb + (q * 32 + jb) * 32);
    const float* ub = U + ((size_t)(b * 96 + iq * 4)) * Hdim + kt * 32 + kq * 4;
    #pragma unroll
    for (int g = 0; g < 4; g++)
      uld[g] = *(const f32x4*)(ub + (size_t)g * Hdim);
  };
  auto buildA = [&](int buf){
    #pragma unroll
    for (int q = 0; q < 3; q++){
      int j = q * 32 + jb;
      f32x4 vf;
      #pragma unroll
      for (int e = 0; e < 4; e++) vf[e] = bf2f(vld[q][e]);
      #pragma unroll
      for (int g = 0; g < 4; g++){
        int row = g * 96 + j;
        ushort4v pk;
        #pragma unroll
        for (int e = 0; e < 4; e++) pk[e] = f2bf(fmaxf(uld[g][e] + vf[e], 0.f));
        int idx = row * 32 + ((kq * 4) ^ ((row & 8) << 1));
        *(ushort4v*)&As[buf][idx] = pk;
      }
    }
  };
  auto mfmaPhase = [&](int buf){
    #pragma unroll
    for (int kh = 0; kh < 2; kh++){
      int gg = kh * 2 + (lane >> 5);
      bf16x8 af[3], bfr[3];
      #pragma unroll
      for (int mf = 0; mf < 3; mf++){
        int row = w * 96 + mf * 32 + (lane & 31);
        af[mf] = *(const bf16x8*)&As[buf][row * 32 + ((gg * 8) ^ ((row & 8) << 1))];
      }
      #pragma unroll
      for (int nf = 0; nf < 3; nf++){
        int n = nf * 32 + (lane & 31);
        bfr[nf] = *(const bf16x8*)&Bs[buf][n * 32 + ((gg * 8) ^ ((n & 8) << 1))];
      }
      __builtin_amdgcn_s_setprio(1);
      #pragma unroll
      for (int mf = 0; mf < 3; mf++)
        #pragma unroll
        for (int nf = 0; nf < 3; nf++)
          acc[mf][nf] = __builtin_amdgcn_mfma_f32_32x32x16_bf16(af[mf], bfr[nf], acc[mf][nf], 0, 0, 0);
      __builtin_amdgcn_s_setprio(0);
    }
  };

  // prologue: stage tile 0
  issueB(0, 0);
  issueUV(0);
  buildA(0);
  __syncthreads();   // barrier drains DMA (vmcnt0) + ds writes

  for (int kt = 0; kt < NKT; kt++){
    int cur = kt & 1;
    if (kt + 1 < NKT){ issueB(kt + 1, cur ^ 1); issueUV(kt + 1); }
    mfmaPhase(cur);
    if (kt + 1 < NKT) buildA(cur ^ 1);
    __syncthreads();
  }

  // epilogue: wave w -> i = iq*4+w; row j -> pair p = i*95 + j - (j>i); skip j==i
  int i = iq * 4 + w;
  size_t outB = (size_t)b * Pdim;
  int colbase = nq * 96;
  float bc[3];
  #pragma unroll
  for (int nf = 0; nf < 3; nf++) bc[nf] = b2[colbase + nf * 32 + (lane & 31)];
  #pragma unroll
  for (int mf = 0; mf < 3; mf++){
    #pragma unroll
    for (int reg = 0; reg < 16; reg++){
      int j = mf * 32 + (reg & 3) + 8 * (reg >> 2) + 4 * (lane >> 5);
      if (j == i) continue;
      int p = i * 95 + j - (j > i ? 1 : 0);
      float* orow = out + (outB + p) * Ddim + colbase;
      #pragma unroll
      for (int nf = 0; nf < 3; nf++){
        int cn = nf * 32 + (lane & 31);
        orow[cn] = acc[mf][nf][reg] + bc[nf];
      }
    }
  }
}

// ---------------- host launch ----------------
extern "C" void kernel_launch(void* const* d_in, const int* in_sizes, int n_in,
                              void* d_out, int out_size, void* d_ws, size_t ws_size,
                              hipStream_t stream)
{
  (void)in_sizes; (void)n_in; (void)out_size;
  const float* h     = (const float*)d_in[0];
  const int*   span  = (const int*)d_in[1];
  const float* ps_w1 = (const float*)d_in[2];
  const float* ps_b1 = (const float*)d_in[3];
  const float* ps_w2 = (const float*)d_in[4];
  const float* ps_b2 = (const float*)d_in[5];
  const float* pe_w1 = (const float*)d_in[6];
  const float* pe_b1 = (const float*)d_in[7];
  const float* pe_w2 = (const float*)d_in[8];
  const float* pe_b2 = (const float*)d_in[9];
  const float* so_w1 = (const float*)d_in[10];
  const float* so_b1 = (const float*)d_in[11];
  const float* so_w2 = (const float*)d_in[12];
  const float* so_b2 = (const float*)d_in[13];
  const float* ro_w1 = (const float*)d_in[14];
  const float* ro_b1 = (const float*)d_in[15];
  const float* ro_w2 = (const float*)d_in[16];
  const float* ro_b2 = (const float*)d_in[17];

  char* ws = (char*)d_ws;
  size_t off = 0;
  auto alloc_us = [&](size_t n)->unsigned short*{
    unsigned short* p = (unsigned short*)(ws + off);
    off += ((n * 2 + 255) & ~(size_t)255);
    return p;
  };
  auto alloc_f = [&](size_t n)->float*{
    float* p = (float*)(ws + off);
    off += ((n * 4 + 255) & ~(size_t)255);
    return p;
  };

  unsigned short* ps1h = alloc_us((size_t)Hdim * Ddim); unsigned short* ps1l = alloc_us((size_t)Hdim * Ddim);
  unsigned short* ps2h = alloc_us((size_t)Ddim * Hdim); unsigned short* ps2l = alloc_us((size_t)Ddim * Hdim);
  unsigned short* pe1h = alloc_us((size_t)Hdim * Ddim); unsigned short* pe1l = alloc_us((size_t)Hdim * Ddim);
  unsigned short* pe2h = alloc_us((size_t)Ddim * Hdim); unsigned short* pe2l = alloc_us((size_t)Ddim * Hdim);
  unsigned short* so1h = alloc_us((size_t)Hdim * 2 * Ddim); unsigned short* so1l = alloc_us((size_t)Hdim * 2 * Ddim);
  unsigned short* so2h = alloc_us((size_t)Ddim * Hdim); unsigned short* so2l = alloc_us((size_t)Ddim * Hdim);
  unsigned short* ro1h = alloc_us((size_t)Hdim * 2 * Ddim); unsigned short* ro1l = alloc_us((size_t)Hdim * 2 * Ddim);
  unsigned short* W2P  = alloc_us((size_t)Ddim * Hdim);        // 8 nq x 96 kt x 3072
  unsigned short* Vp   = alloc_us((size_t)Bdim * Kspan * Hdim); // 4 b x 96 kt x 3072
  float* hg     = alloc_f((size_t)2 * MROWS * Ddim);
  float* mid_s  = alloc_f((size_t)MROWS * Hdim);
  float* mid_e  = alloc_f((size_t)MROWS * Hdim);
  float* cat    = alloc_f((size_t)MROWS * 2 * Ddim);
  float* entity = alloc_f((size_t)MROWS * Ddim);
  float* Ubuf   = alloc_f((size_t)MROWS * Hdim);
  float* Vbuf   = alloc_f((size_t)MROWS * Hdim);
  const size_t MN = (size_t)MROWS * Ddim;
  float* P2 = alloc_f(8 * MN);
  float* P3 = alloc_f(4 * MN);
  if (off > ws_size) return;

  dim3 tb(256);
  transpose_split<<<dim3(Hdim/64, Ddim/64), tb, 0, stream>>>(ps_w1, ps1h, ps1l, Ddim, Hdim);
  transpose_split<<<dim3(Ddim/64, Hdim/64), tb, 0, stream>>>(ps_w2, ps2h, ps2l, Hdim, Ddim);
  transpose_split<<<dim3(Hdim/64, Ddim/64), tb, 0, stream>>>(pe_w1, pe1h, pe1l, Ddim, Hdim);
  transpose_split<<<dim3(Ddim/64, Hdim/64), tb, 0, stream>>>(pe_w2, pe2h, pe2l, Hdim, Ddim);
  transpose_split<<<dim3(Hdim/64, (2*Ddim)/64), tb, 0, stream>>>(so_w1, so1h, so1l, 2*Ddim, Hdim);
  transpose_split<<<dim3(Ddim/64, Hdim/64), tb, 0, stream>>>(so_w2, so2h, so2l, Hdim, Ddim);
  transpose_split<<<dim3(Hdim/64, (2*Ddim)/64), tb, 0, stream>>>(ro_w1, ro1h, ro1l, 2*Ddim, Hdim);
  pack_w2<<<dim3(NKT, 8), tb, 0, stream>>>(ro_w2, W2P);

  gather_rows<<<2 * MROWS, tb, 0, stream>>>(h, span, hg);

  // L1: start/end first linear (merged), M=384 N=3072 K=768
  {
    GJob j0{hg,                      ps1h, ps1l, ps_b1, mid_s};
    GJob j1{hg + (size_t)MROWS*Ddim, pe1h, pe1l, pe_b1, mid_e};
    gemm_ms<0,1><<<dim3(Hdim/128, MROWS/64, 2), tb, 0, stream>>>(j0, j1, Ddim, Ddim, Hdim, Ddim, 0);
  }
  // L2: start/end second linear (merged, split-K=4) -> partials
  {
    GJob j0{mid_s, ps2h, ps2l, nullptr, P2};
    GJob j1{mid_e, pe2h, pe2l, nullptr, P2 + 4*MN};
    gemm_ms<2,4><<<dim3(Ddim/128, MROWS/64, 8), tb, 0, stream>>>(j0, j1, Hdim, Hdim, Ddim, Hdim/4, MN);
  }
  reduce_part<true><<<(2*(int)MN)/1024, tb, 0, stream>>>(P2, 4, ps_b2, pe_b2, cat, 2, 2*Ddim);
  // so1: M=384 N=3072 K=1536
  {
    GJob j0{cat, so1h, so1l, so_b1, mid_s};
    gemm_ms<0,1><<<dim3(Hdim/128, MROWS/64, 1), tb, 0, stream>>>(j0, j0, 2*Ddim, 2*Ddim, Hdim, 2*Ddim, 0);
  }
  // so2: split-K=4 -> partials (no relu on entity)
  {
    GJob j0{mid_s, so2h, so2l, nullptr, P3};
    gemm_ms<2,4><<<dim3(Ddim/128, MROWS/64, 4), tb, 0, stream>>>(j0, j0, Hdim, Hdim, Ddim, Hdim/4, MN);
  }
  reduce_part<false><<<((int)MN)/1024, tb, 0, stream>>>(P3, 4, so_b2, so_b2, entity, 1, Ddim);
  // U = entity @ ro_w1_top + ro_b1 ; V = entity @ ro_w1_bot (merged)
  {
    GJob j0{entity, ro1h,        ro1l,        ro_b1,   Ubuf};
    GJob j1{entity, ro1h + Ddim, ro1l + Ddim, nullptr, Vbuf};
    gemm_ms<1,1><<<dim3(Hdim/128, MROWS/64, 2), tb, 0, stream>>>(j0, j1, Ddim, 2*Ddim, Hdim, Ddim, 0);
  }
  pack_v<<<dim3(NKT, Bdim), tb, 0, stream>>>(Vbuf, Vp);

  // fused pair GEMM v3
  pair_gemm3<<<768, tb, 0, stream>>>(Ubuf, Vp, W2P, ro_b2, (float*)d_out);
}

// Round 4
// 470.677 us; speedup vs baseline: 1.7795x; 1.1283x over previous
//
#include <hip/hip_runtime.h>
#include <hip/hip_bf16.h>

// ---- problem dims (fixed) ----
#define Bdim 4
#define Ldim 512
#define Ddim 768
#define Kspan 96
#define Hdim 3072
#define Pdim 9120      // Kspan*(Kspan-1)
#define MROWS 384      // Bdim*Kspan
#define NKT4 48        // Hdim/64: K-tiles for pair kernel (BK=64)

typedef __bf16 bf16x8 __attribute__((ext_vector_type(8)));
typedef float f32x4 __attribute__((ext_vector_type(4)));
typedef float f32x16 __attribute__((ext_vector_type(16)));
typedef unsigned short ushort8v __attribute__((ext_vector_type(8)));

static __device__ __forceinline__ unsigned short f2bf(float x){
  return __builtin_bit_cast(unsigned short, (__bf16)x);
}
static __device__ __forceinline__ float bf2f(unsigned short u){
  return (float)__builtin_bit_cast(__bf16, u);
}
static __device__ __forceinline__ float bfbits2f(unsigned short u){
  return __builtin_bit_cast(float, (unsigned)u << 16);
}

// ---------------- merged transpose+split: W[K][N] f32 -> WT[N][K] bf16 hi+lo -------------
struct TJob { const float* W; unsigned short* Th; unsigned short* Tl; int K; int N; int base; };
struct TJobs { TJob j[7]; };

__global__ __launch_bounds__(256) void transpose_multi(TJobs JJ)
{
  int x = blockIdx.x;
  int ji = 0;
  #pragma unroll
  for (int q = 1; q < 7; q++) if (x >= JJ.j[q].base) ji = q;
  TJob J = JJ.j[ji];
  int local = x - J.base;
  int tilesX = J.N >> 6;
  int bx = local % tilesX, by = local / tilesX;
  __shared__ float tile[64][65];
  int k0 = by * 64, n0 = bx * 64;
  int c = threadIdx.x & 63, r0 = threadIdx.x >> 6;
  for (int p = 0; p < 16; p++){
    int r = r0 + p * 4;
    tile[c][r] = J.W[(size_t)(k0 + r) * J.N + n0 + c];
  }
  __syncthreads();
  for (int p = 0; p < 16; p++){
    int n = r0 + p * 4;
    float xv = tile[n][c];
    unsigned short h = f2bf(xv);
    size_t o = (size_t)(n0 + n) * J.K + k0 + c;
    J.Th[o] = h;
    J.Tl[o] = f2bf(xv - bf2f(h));
  }
}

// ---------------- pack ro_w2 [Hdim][Ddim] f32 -> W2P bf16, pre-swizzled ------------------
// Tile (nq in 0..3, kt in 0..47): 192 n-rows x 64 k shorts, 128B rows.
// Phys short index o: n = o>>6, kph = o&63, logical ks = kph ^ ((n&7)<<3)  (involution).
__global__ __launch_bounds__(256) void pack_w2(
    const float* __restrict__ W, unsigned short* __restrict__ W2P)
{
  __shared__ float tile[64][193];
  int kt = blockIdx.x, nq = blockIdx.y, t = threadIdx.x;
  for (int q = 0; q < 48; q++){
    int flat = q * 256 + t;             // 0..12287
    int ks = flat / 192, n = flat - ks * 192;
    tile[ks][n] = W[(size_t)(kt * 64 + ks) * Ddim + nq * 192 + n];
  }
  __syncthreads();
  unsigned short* outp = W2P + (size_t)(nq * 48 + kt) * 12288;
  for (int q = 0; q < 48; q++){
    int o = q * 256 + t;
    int n = o >> 6, kph = o & 63;
    int ks = kph ^ ((n & 7) << 3);
    outp[o] = f2bf(tile[ks][n]);
  }
}

// ---------------- pack Vbuf f32 [MROWS][Hdim] -> Vp bf16 per (b,kt), pre-swizzled --------
// Tile (b, kt): 96 j-rows x 64 k shorts, 128B rows, same XOR swizzle on 8-short granules.
__global__ __launch_bounds__(256) void pack_v(
    const float* __restrict__ Vbuf, unsigned short* __restrict__ Vp)
{
  int kt = blockIdx.x, b = blockIdx.y, t = threadIdx.x;
  unsigned short* outp = Vp + (size_t)(b * 48 + kt) * 6144;
  #pragma unroll
  for (int q = 0; q < 3; q++){
    int item = q * 256 + t;             // 0..767
    int j = item >> 3, g = item & 7;
    const float* src = Vbuf + (size_t)(b * 96 + j) * Hdim + kt * 64 + g * 8;
    f32x4 a0 = *(const f32x4*)src, a1 = *(const f32x4*)(src + 4);
    ushort8v pk;
    #pragma unroll
    for (int e = 0; e < 4; e++) pk[e] = f2bf(a0[e]);
    #pragma unroll
    for (int e = 0; e < 4; e++) pk[e + 4] = f2bf(a1[e]);
    *(ushort8v*)(outp + j * 64 + ((g ^ (j & 7)) << 3)) = pk;
  }
}

// ---------------- gather h rows at span indices (fp32 copy) ----------------
__global__ __launch_bounds__(256) void gather_rows(
    const float* __restrict__ h, const int* __restrict__ span, float* __restrict__ hg)
{
  int x = blockIdx.x;            // 0 .. 2*MROWS-1
  int sel = (x >= MROWS) ? 1 : 0;
  int r = x - sel * MROWS;
  int b = r / Kspan, k = r - b * Kspan;
  int idx = span[(b * Kspan + k) * 2 + sel];
  const float* src = h + ((size_t)b * Ldim + idx) * Ddim;
  float* dst = hg + (size_t)x * Ddim;
  for (int d = threadIdx.x; d < Ddim; d += 256) dst[d] = src[d];
}

// ---------------- split-bf16 GEMM (multi-job + optional split-K) ------------------------
struct GJob {
  const float* A;
  const unsigned short* Wh;
  const unsigned short* Wl;
  const float* bias;
  float* C;
};

template<int MODE, int SPLIT>
__global__ __launch_bounds__(256) void gemm_ms(
    GJob j0, GJob j1, int ldA, int ldW, int ldC, int kLen, size_t csz)
{
  constexpr int SR = 40;
  __shared__ __align__(16) unsigned short Ah[64 * SR], Al[64 * SR];
  __shared__ __align__(16) unsigned short Bh[128 * SR], Bl[128 * SR];
  int zj, s;
  if (SPLIT == 1){ zj = blockIdx.z; s = 0; }
  else { zj = blockIdx.z / SPLIT; s = blockIdx.z % SPLIT; }
  const GJob J = zj ? j1 : j0;
  int kBegin = s * kLen;
  float* Cptr = (MODE == 2) ? (J.C + (size_t)s * csz) : J.C;

  int m0 = blockIdx.y * 64, n0 = blockIdx.x * 128;
  int t = threadIdx.x, lane = t & 63, wid = t >> 6;
  int wm = wid >> 1, wn = wid & 1;
  int lr = lane & 15, lk = (lane >> 4) * 8;
  f32x4 acc[2][4] = {};
  int ar = t >> 2, akq = t & 3;
  for (int k0 = 0; k0 < kLen; k0 += 32){
    {
      const float* sp = J.A + (size_t)(m0 + ar) * ldA + kBegin + k0 + akq * 8;
      f32x4 x0 = *(const f32x4*)sp, x1 = *(const f32x4*)(sp + 4);
      ushort8v vh, vl;
      for (int e = 0; e < 4; e++){ float x = x0[e]; unsigned short hh = f2bf(x); vh[e] = hh; vl[e] = f2bf(x - bf2f(hh)); }
      for (int e = 0; e < 4; e++){ float x = x1[e]; unsigned short hh = f2bf(x); vh[e+4] = hh; vl[e+4] = f2bf(x - bf2f(hh)); }
      *(ushort8v*)&Ah[ar * SR + akq * 8] = vh;
      *(ushort8v*)&Al[ar * SR + akq * 8] = vl;
    }
    for (int p = 0; p < 2; p++){
      int idx = p * 256 + t; int n = idx >> 2, kq = idx & 3;
      size_t go = (size_t)(n0 + n) * ldW + kBegin + k0 + kq * 8;
      *(ushort8v*)&Bh[n * SR + kq * 8] = *(const ushort8v*)(J.Wh + go);
      *(ushort8v*)&Bl[n * SR + kq * 8] = *(const ushort8v*)(J.Wl + go);
    }
    __syncthreads();
    bf16x8 ah[2], al2[2], bh[4], bl[4];
    for (int f = 0; f < 2; f++){ int o = (wm * 32 + f * 16 + lr) * SR + lk; ah[f] = *(const bf16x8*)&Ah[o]; al2[f] = *(const bf16x8*)&Al[o]; }
    for (int g = 0; g < 4; g++){ int o = (wn * 64 + g * 16 + lr) * SR + lk; bh[g] = *(const bf16x8*)&Bh[o]; bl[g] = *(const bf16x8*)&Bl[o]; }
    for (int f = 0; f < 2; f++)
      for (int g = 0; g < 4; g++){
        acc[f][g] = __builtin_amdgcn_mfma_f32_16x16x32_bf16(ah[f],  bh[g], acc[f][g], 0, 0, 0);
        acc[f][g] = __builtin_amdgcn_mfma_f32_16x16x32_bf16(ah[f],  bl[g], acc[f][g], 0, 0, 0);
        acc[f][g] = __builtin_amdgcn_mfma_f32_16x16x32_bf16(al2[f], bh[g], acc[f][g], 0, 0, 0);
      }
    __syncthreads();
  }
  int rr = (lane >> 4) * 4;
  for (int f = 0; f < 2; f++){
    int gm = m0 + wm * 32 + f * 16 + rr;
    for (int g = 0; g < 4; g++){
      int gn = n0 + wn * 64 + g * 16 + (lane & 15);
      float bv = (MODE != 2 && J.bias) ? J.bias[gn] : 0.f;
      for (int r2 = 0; r2 < 4; r2++){
        float v = acc[f][g][r2] + bv;
        if (MODE == 0) v = fmaxf(v, 0.f);
        Cptr[(size_t)(gm + r2) * ldC + gn] = v;
      }
    }
  }
}

// ---------------- split-K partial reduce ----------------
template<bool RELU>
__global__ __launch_bounds__(256) void reduce_part(
    const float* __restrict__ P, int S,
    const float* __restrict__ bias0, const float* __restrict__ bias1,
    float* __restrict__ outp, int zCount, int ldOut)
{
  const int MN = MROWS * Ddim;
  int idx4 = blockIdx.x * 256 + threadIdx.x;
  int flat = idx4 * 4;
  if (flat >= MN * zCount) return;
  int z = flat / MN; int rem = flat - z * MN;
  int r = rem / Ddim; int c = rem - r * Ddim;
  const float* base = P + (size_t)z * S * MN + rem;
  f32x4 sv = *(const f32x4*)base;
  for (int ss = 1; ss < S; ss++){ f32x4 v = *(const f32x4*)(base + (size_t)ss * MN); sv += v; }
  const float* bp = z ? bias1 : bias0;
  f32x4 bv = *(const f32x4*)(bp + c);
  sv += bv;
  if (RELU) for (int e = 0; e < 4; e++) sv[e] = fmaxf(sv[e], 0.f);
  *(f32x4*)(outp + (size_t)r * ldOut + z * Ddim + c) = sv;
}

// ---------------- fused pair GEMM v4 --------------------------------------------------
// Block: (nq in 0..3, b in 0..3, ig in 0..47).  M = 192 (2 i's x 96 j), N = 192, BK = 64.
// 4 waves (2x2): wave (wm,wn) computes i = ig*2+wm, cols wn*96.. (wave tile 96x96,
// mfma_f32_32x32x16, acc 3x3 f32x16).  A-fragments built IN REGISTERS from V (LDS) + U
// (regs).  V and B staged by global_load_lds from pre-swizzled packed buffers (128B rows,
// byte ^= (row&7)<<4 -- m214-proven conflict-free pattern).  One barrier per K-tile.
__global__ __launch_bounds__(256, 2) void pair_gemm4(
    const float* __restrict__ U,            // [MROWS][Hdim] f32, ro_b1 folded
    const unsigned short* __restrict__ Vp,  // per (b,kt): swizzled [96 j][64 k] bf16
    const unsigned short* __restrict__ W2P, // per (nq,kt): swizzled [192 n][64 k] bf16
    const float* __restrict__ b2,           // [Ddim]
    float* __restrict__ out)                // [Bdim*Pdim][Ddim]
{
  __shared__ __align__(16) unsigned short Bs[2][12288]; // 2 x 24 KiB
  __shared__ __align__(16) unsigned short Vs[2][6144];  // 2 x 12 KiB

  // XCD-combo mapping: each XCD works one (nq,b) slice (B panel 1.2MB + V/U ~1.8MB in L2)
  int x = blockIdx.x;
  int xcd = x & 7;
  int s = x >> 3;                  // 0..95
  int combo = xcd + ((s >= 48) ? 8 : 0);
  int ig = (s >= 48) ? (s - 48) : s;
  int nq = combo & 3, b = combo >> 2;

  int t = threadIdx.x, lane = t & 63, w = t >> 6;
  int wm = w >> 1, wn = w & 1;
  int l31 = lane & 31, hsel = lane >> 5;
  int i = ig * 2 + wm;
  const float* Urow = U + ((size_t)(b * 96 + i)) * Hdim + hsel * 8;

  f32x16 acc[3][3] = {};

  auto issueB = [&](int kt, int buf){
    const unsigned short* srcb = W2P + (size_t)(nq * 48 + kt) * 12288 + t * 8;
    #pragma unroll
    for (int q = 0; q < 6; q++){
      __builtin_amdgcn_global_load_lds(
          (const __attribute__((address_space(1))) unsigned int*)(srcb + q * 2048),
          (__attribute__((address_space(3))) unsigned int*)&Bs[buf][q * 2048 + t * 8],
          16, 0, 0);
    }
  };
  auto issueV = [&](int kt, int buf){
    const unsigned short* srcv = Vp + (size_t)(b * 48 + kt) * 6144 + t * 8;
    #pragma unroll
    for (int q = 0; q < 3; q++){
      __builtin_amdgcn_global_load_lds(
          (const __attribute__((address_space(1))) unsigned int*)(srcv + q * 2048),
          (__attribute__((address_space(3))) unsigned int*)&Vs[buf][q * 2048 + t * 8],
          16, 0, 0);
    }
  };

  // prologue
  issueB(0, 0);
  issueV(0, 0);
  __syncthreads();

  for (int kt = 0; kt < NKT4; kt++){
    int cur = kt & 1;
    if (kt + 1 < NKT4){ issueB(kt + 1, cur ^ 1); issueV(kt + 1, cur ^ 1); }

    // U slices for this K-tile: lane needs k-granules g = kh*2 + hsel
    float uf[4][8];
    {
      const float* ub = Urow + kt * 64;
      #pragma unroll
      for (int kh = 0; kh < 4; kh++){
        *(f32x4*)&uf[kh][0] = *(const f32x4*)(ub + kh * 16);
        *(f32x4*)&uf[kh][4] = *(const f32x4*)(ub + kh * 16 + 4);
      }
    }

    #pragma unroll
    for (int kh = 0; kh < 4; kh++){
      int gx16 = (kh * 2 + hsel) * 16;
      bf16x8 bfr[3], afr[3];
      #pragma unroll
      for (int nf = 0; nf < 3; nf++){
        int n = wn * 96 + nf * 32 + l31;
        bfr[nf] = *(const bf16x8*)((const char*)&Bs[cur][0] + n * 128 + (gx16 ^ ((n & 7) << 4)));
      }
      #pragma unroll
      for (int mf = 0; mf < 3; mf++){
        int j = mf * 32 + l31;
        ushort8v vv = *(const ushort8v*)((const char*)&Vs[cur][0] + j * 128 + (gx16 ^ ((j & 7) << 4)));
        ushort8v pk;
        #pragma unroll
        for (int e = 0; e < 8; e++)
          pk[e] = f2bf(fmaxf(uf[kh][e] + bfbits2f(vv[e]), 0.f));
        afr[mf] = __builtin_bit_cast(bf16x8, pk);
      }
      __builtin_amdgcn_s_setprio(1);
      #pragma unroll
      for (int mf = 0; mf < 3; mf++)
        #pragma unroll
        for (int nf = 0; nf < 3; nf++)
          acc[mf][nf] = __builtin_amdgcn_mfma_f32_32x32x16_bf16(afr[mf], bfr[nf], acc[mf][nf], 0, 0, 0);
      __builtin_amdgcn_s_setprio(0);
    }
    __syncthreads();
  }

  // epilogue: row j -> pair p = i*95 + j - (j>i); skip j==i
  size_t outB = (size_t)b * Pdim;
  int colbase = nq * 192 + wn * 96;
  float bc[3];
  #pragma unroll
  for (int nf = 0; nf < 3; nf++) bc[nf] = b2[colbase + nf * 32 + l31];
  #pragma unroll
  for (int mf = 0; mf < 3; mf++){
    #pragma unroll
    for (int reg = 0; reg < 16; reg++){
      int j = mf * 32 + (reg & 3) + 8 * (reg >> 2) + 4 * hsel;
      if (j == i) continue;
      int p = i * 95 + j - (j > i ? 1 : 0);
      float* orow = out + (outB + p) * Ddim + colbase;
      #pragma unroll
      for (int nf = 0; nf < 3; nf++)
        orow[nf * 32 + l31] = acc[mf][nf][reg] + bc[nf];
    }
  }
}

// ---------------- host launch ----------------
extern "C" void kernel_launch(void* const* d_in, const int* in_sizes, int n_in,
                              void* d_out, int out_size, void* d_ws, size_t ws_size,
                              hipStream_t stream)
{
  (void)in_sizes; (void)n_in; (void)out_size;
  const float* h     = (const float*)d_in[0];
  const int*   span  = (const int*)d_in[1];
  const float* ps_w1 = (const float*)d_in[2];
  const float* ps_b1 = (const float*)d_in[3];
  const float* ps_w2 = (const float*)d_in[4];
  const float* ps_b2 = (const float*)d_in[5];
  const float* pe_w1 = (const float*)d_in[6];
  const float* pe_b1 = (const float*)d_in[7];
  const float* pe_w2 = (const float*)d_in[8];
  const float* pe_b2 = (const float*)d_in[9];
  const float* so_w1 = (const float*)d_in[10];
  const float* so_b1 = (const float*)d_in[11];
  const float* so_w2 = (const float*)d_in[12];
  const float* so_b2 = (const float*)d_in[13];
  const float* ro_w1 = (const float*)d_in[14];
  const float* ro_b1 = (const float*)d_in[15];
  const float* ro_w2 = (const float*)d_in[16];
  const float* ro_b2 = (const float*)d_in[17];

  char* ws = (char*)d_ws;
  size_t off = 0;
  auto alloc_us = [&](size_t n)->unsigned short*{
    unsigned short* p = (unsigned short*)(ws + off);
    off += ((n * 2 + 255) & ~(size_t)255);
    return p;
  };
  auto alloc_f = [&](size_t n)->float*{
    float* p = (float*)(ws + off);
    off += ((n * 4 + 255) & ~(size_t)255);
    return p;
  };

  unsigned short* ps1h = alloc_us((size_t)Hdim * Ddim); unsigned short* ps1l = alloc_us((size_t)Hdim * Ddim);
  unsigned short* ps2h = alloc_us((size_t)Ddim * Hdim); unsigned short* ps2l = alloc_us((size_t)Ddim * Hdim);
  unsigned short* pe1h = alloc_us((size_t)Hdim * Ddim); unsigned short* pe1l = alloc_us((size_t)Hdim * Ddim);
  unsigned short* pe2h = alloc_us((size_t)Ddim * Hdim); unsigned short* pe2l = alloc_us((size_t)Ddim * Hdim);
  unsigned short* so1h = alloc_us((size_t)Hdim * 2 * Ddim); unsigned short* so1l = alloc_us((size_t)Hdim * 2 * Ddim);
  unsigned short* so2h = alloc_us((size_t)Ddim * Hdim); unsigned short* so2l = alloc_us((size_t)Ddim * Hdim);
  unsigned short* ro1h = alloc_us((size_t)Hdim * 2 * Ddim); unsigned short* ro1l = alloc_us((size_t)Hdim * 2 * Ddim);
  unsigned short* W2P  = alloc_us((size_t)4 * 48 * 12288);  // 2.36M shorts
  unsigned short* Vp   = alloc_us((size_t)4 * 48 * 6144);   // 1.18M shorts
  float* hg     = alloc_f((size_t)2 * MROWS * Ddim);
  float* mid_s  = alloc_f((size_t)MROWS * Hdim);
  float* mid_e  = alloc_f((size_t)MROWS * Hdim);
  float* cat    = alloc_f((size_t)MROWS * 2 * Ddim);
  float* entity = alloc_f((size_t)MROWS * Ddim);
  float* Ubuf   = alloc_f((size_t)MROWS * Hdim);
  float* Vbuf   = alloc_f((size_t)MROWS * Hdim);
  const size_t MN = (size_t)MROWS * Ddim;
  float* P2 = alloc_f(8 * MN);
  float* P3 = alloc_f(4 * MN);
  if (off > ws_size) return;

  dim3 tb(256);

  // merged weight transposes (7 jobs)
  {
    TJobs JJ;
    int base = 0;
    auto add = [&](int idx, const float* W, unsigned short* Th, unsigned short* Tl, int K, int N){
      JJ.j[idx] = TJob{W, Th, Tl, K, N, base};
      base += (N / 64) * (K / 64);
    };
    add(0, ps_w1, ps1h, ps1l, Ddim, Hdim);
    add(1, ps_w2, ps2h, ps2l, Hdim, Ddim);
    add(2, pe_w1, pe1h, pe1l, Ddim, Hdim);
    add(3, pe_w2, pe2h, pe2l, Hdim, Ddim);
    add(4, so_w1, so1h, so1l, 2 * Ddim, Hdim);
    add(5, so_w2, so2h, so2l, Hdim, Ddim);
    add(6, ro_w1, ro1h, ro1l, 2 * Ddim, Hdim);
    transpose_multi<<<base, tb, 0, stream>>>(JJ);
  }
  pack_w2<<<dim3(NKT4, 4), tb, 0, stream>>>(ro_w2, W2P);

  gather_rows<<<2 * MROWS, tb, 0, stream>>>(h, span, hg);

  // L1: start/end first linear (merged), M=384 N=3072 K=768
  {
    GJob j0{hg,                      ps1h, ps1l, ps_b1, mid_s};
    GJob j1{hg + (size_t)MROWS*Ddim, pe1h, pe1l, pe_b1, mid_e};
    gemm_ms<0,1><<<dim3(Hdim/128, MROWS/64, 2), tb, 0, stream>>>(j0, j1, Ddim, Ddim, Hdim, Ddim, 0);
  }
  // L2: start/end second linear (merged, split-K=4) -> partials
  {
    GJob j0{mid_s, ps2h, ps2l, nullptr, P2};
    GJob j1{mid_e, pe2h, pe2l, nullptr, P2 + 4*MN};
    gemm_ms<2,4><<<dim3(Ddim/128, MROWS/64, 8), tb, 0, stream>>>(j0, j1, Hdim, Hdim, Ddim, Hdim/4, MN);
  }
  reduce_part<true><<<(2*(int)MN)/1024, tb, 0, stream>>>(P2, 4, ps_b2, pe_b2, cat, 2, 2*Ddim);
  // so1: M=384 N=3072 K=1536
  {
    GJob j0{cat, so1h, so1l, so_b1, mid_s};
    gemm_ms<0,1><<<dim3(Hdim/128, MROWS/64, 1), tb, 0, stream>>>(j0, j0, 2*Ddim, 2*Ddim, Hdim, 2*Ddim, 0);
  }
  // so2: split-K=4 -> partials (no relu on entity)
  {
    GJob j0{mid_s, so2h, so2l, nullptr, P3};
    gemm_ms<2,4><<<dim3(Ddim/128, MROWS/64, 4), tb, 0, stream>>>(j0, j0, Hdim, Hdim, Ddim, Hdim/4, MN);
  }
  reduce_part<false><<<((int)MN)/1024, tb, 0, stream>>>(P3, 4, so_b2, so_b2, entity, 1, Ddim);
  // U = entity @ ro_w1_top + ro_b1 ; V = entity @ ro_w1_bot (merged)
  {
    GJob j0{entity, ro1h,        ro1l,        ro_b1,   Ubuf};
    GJob j1{entity, ro1h + Ddim, ro1l + Ddim, nullptr, Vbuf};
    gemm_ms<1,1><<<dim3(Hdim/128, MROWS/64, 2), tb, 0, stream>>>(j0, j1, Ddim, 2*Ddim, Hdim, Ddim, 0);
  }
  pack_v<<<dim3(NKT4, Bdim), tb, 0, stream>>>(Vbuf, Vp);

  // fused pair GEMM v4
  pair_gemm4<<<768, tb, 0, stream>>>(Ubuf, Vp, W2P, ro_b2, (float*)d_out);
}